// Round 6
// baseline (442.887 us; speedup 1.0000x reference)
//
#include <hip/hip_runtime.h>
#include <hip/hip_bf16.h>
#include <math.h>

#define NB 16384

typedef __bf16 bf16x8 __attribute__((ext_vector_type(8)));
typedef __fp16 f16x8  __attribute__((ext_vector_type(8)));
typedef float  f32x4  __attribute__((ext_vector_type(4)));
typedef unsigned short ushort8 __attribute__((ext_vector_type(8)));

__device__ __forceinline__ float selu_f(float x) {
    const float kScale = 1.0507009873554805f;
    const float kAlphaScale = 1.7580993408473766f;   // scale*alpha
    return x > 0.0f ? kScale * x : kAlphaScale * (__expf(x) - 1.0f);
}

__device__ __forceinline__ unsigned short f2bf(float x) {   // RNE
    unsigned int u = __float_as_uint(x);
    unsigned int r = (u + 0x7FFFu + ((u >> 16) & 1u)) >> 16;
    return (unsigned short)r;
}

// ---------------------------------------------------------------------------
// Kernel P (prep): builds all weight-derived tables in ws.
//  1. dec2_w  -> bf16 wbf                               (125440)
//  2. lin1_w  -> lin1_wp permuted for new x2 layout     (16000)
//     x2 new layout: [b][q*20 + oc]  (old: oc*16 + q)
//  3. woff[k] -> x1 float offset of k-th conv2 reduction elem (256)
//  4. conv2_w -> whi/wlo fp16 split, B-fragment order   (2 x 8192)
//     layout: [(nt*8+s)*64 + lane]*8 + j  with oc = nt*16+(lane&15),
//             k = s*32 + (lane>>4)*8 + j
// ---------------------------------------------------------------------------
__global__ __launch_bounds__(256) void k_prep(
    const float* __restrict__ dec2_w,  unsigned short* __restrict__ wbf,
    const float* __restrict__ lin1_w,  float* __restrict__ lin1_wp,
    const float* __restrict__ conv2_w, unsigned short* __restrict__ woff,
    __fp16* __restrict__ whi, __fp16* __restrict__ wlo)
{
    int i = blockIdx.x * 256 + threadIdx.x;
    if (i < 125440) { wbf[i] = f2bf(dec2_w[i]); return; }
    i -= 125440;
    if (i < 16000) {                       // lin1 permute
        const int row = i / 320, cn = i - row * 320;
        const int q = cn / 20, oc = cn - q * 20;
        lin1_wp[row * 320 + cn] = lin1_w[row * 320 + oc * 16 + q];
        return;
    }
    i -= 16000;
    if (i < 256) {                         // A-gather offsets
        unsigned short off = 0;
        if (i < 250) {
            const int ic = i / 25, r = i - ic * 25, ky = r / 5, kx = r - ky * 5;
            off = (unsigned short)(ic * 144 + ky * 12 + kx);
        }
        woff[i] = off;
        return;
    }
    i -= 256;
    if (i < 16384) {                       // conv2 weight split tables
        const int v = i >> 13;             // 0 = hi, 1 = lo
        const int r = i & 8191;
        const int j = r & 7, lane = (r >> 3) & 63, s = (r >> 9) & 7, nt = r >> 12;
        const int k  = s * 32 + (lane >> 4) * 8 + j;
        const int oc = nt * 16 + (lane & 15);
        float w = 0.f;
        if (k < 250 && oc < 20) {
            const int ic = k / 25, rr = k - ic * 25;
            w = conv2_w[(oc * 10 + ic) * 25 + rr];
        }
        const __fp16 hi = (__fp16)w;
        if (v == 0) whi[r] = hi;
        else        wlo[r] = (__fp16)(w - (float)hi);
    }
}

// ---------------------------------------------------------------------------
// Kernel A: conv1(1->10,5x5)+pool+selu (fp32 VALU)  ->  sX1 in LDS  ->
//           conv2(10->20,5x5) as split-fp16 MFMA GEMM (M=256,N=2x16,K=8x32)
//           + pool + bias + selu  ->  x2[b][q*20+oc]
// Row remap: GEMM row = img*64 + q*4 + (dy*2+dx) so each pool quad lands in
// one lane's 4 D-registers. Split a=ah+al, b=bh+bl; ah*bh+al*bh+ah*bl gives
// ~2^-22 rel error (fp32-class) — safe for the code/SVD path.
// launch_bounds(256,4): do NOT raise (r4: (256,6) spilled, 10x regression).
// ---------------------------------------------------------------------------
#define X1S 1440

__global__ __launch_bounds__(256, 4) void k_conv_fused(
    const float* __restrict__ images,
    const float* __restrict__ conv1_w, const float* __restrict__ conv1_b,
    const float* __restrict__ conv2_b,
    const unsigned short* __restrict__ woff,
    const __fp16* __restrict__ whi, const __fp16* __restrict__ wlo,
    float* __restrict__ x2)
{
    __shared__ float sX1[4][X1S];

    const int t  = threadIdx.x;
    const int b0 = blockIdx.x * 4;

    // ---- phase 1: conv1 + pool + selu -> sX1[img][c*144 + pos] ----
    #pragma unroll
    for (int it = 0; it < 3; ++it) {
        const int item = it * 256 + t;
        if (item < 576) {
            const int img = item / 144;
            const int pos = item - img * 144;
            const int py  = pos / 12;
            const int px  = pos - py * 12;
            float p[36];
            const float* bp = images + (size_t)(b0 + img) * 784 + (2 * py) * 28 + 2 * px;
            #pragma unroll
            for (int r = 0; r < 6; ++r) {
                #pragma unroll
                for (int c2 = 0; c2 < 3; ++c2) {
                    const float2 v = *reinterpret_cast<const float2*>(bp + r * 28 + c2 * 2);
                    p[r * 6 + c2 * 2]     = v.x;
                    p[r * 6 + c2 * 2 + 1] = v.y;
                }
            }
            float* x1 = sX1[img];
            #pragma unroll
            for (int c = 0; c < 10; ++c) {
                const float* w = conv1_w + c * 25;   // uniform -> s_load
                float s0 = 0.f, s1 = 0.f, s2 = 0.f, s3 = 0.f;
                #pragma unroll
                for (int ky = 0; ky < 5; ++ky) {
                    #pragma unroll
                    for (int kx = 0; kx < 5; ++kx) {
                        const float wq = w[ky * 5 + kx];
                        s0 = fmaf(p[ky * 6 + kx],           wq, s0);
                        s1 = fmaf(p[ky * 6 + kx + 1],       wq, s1);
                        s2 = fmaf(p[(ky + 1) * 6 + kx],     wq, s2);
                        s3 = fmaf(p[(ky + 1) * 6 + kx + 1], wq, s3);
                    }
                }
                const float m = fmaxf(fmaxf(s0, s1), fmaxf(s2, s3)) + conv1_b[c];
                x1[c * 144 + pos] = selu_f(m);
            }
        }
    }
    __syncthreads();

    // ---- phase 2: conv2 via MFMA. wave w owns image w (m-tiles 4w..4w+3) --
    {
        const int lane = t & 63;
        const int wv   = t >> 6;
        const float* x1 = sX1[wv];
        const int g  = lane >> 4;          // k-group
        const int c0 = lane & 15;          // B col within tile / D col

        // hoisted per-lane A-offset table: 8 k-steps x 8 ushorts
        ushort8 offs[8];
        #pragma unroll
        for (int s = 0; s < 8; ++s)
            offs[s] = *reinterpret_cast<const ushort8*>(woff + s * 32 + g * 8);

        const float bias0 = conv2_b[c0];                       // c0 < 16 < 20
        const float bias1 = (c0 < 4) ? conv2_b[16 + c0] : 0.f;

        for (int mi = 0; mi < 4; ++mi) {
            const int mt  = wv * 4 + mi;
            // A-row geometry for this lane (row = mt*16 + (lane&15))
            const int r64 = (mt & 3) * 16 + c0;
            const int qi  = r64 >> 2;      // pooled pos 0..15
            const int sub = r64 & 3;
            const int yy  = 2 * (qi >> 2) + (sub >> 1);
            const int xx  = 2 * (qi & 3) + (sub & 1);
            const int rowbase = yy * 12 + xx;

            f32x4 acc0 = {0.f, 0.f, 0.f, 0.f};
            f32x4 acc1 = {0.f, 0.f, 0.f, 0.f};
            #pragma unroll
            for (int s = 0; s < 8; ++s) {
                float av[8];
                #pragma unroll
                for (int j = 0; j < 8; ++j)
                    av[j] = x1[rowbase + (int)offs[s][j]];
                f16x8 ah, al;
                #pragma unroll
                for (int j = 0; j < 8; ++j) {
                    const __fp16 h = (__fp16)av[j];
                    ah[j] = h;
                    al[j] = (__fp16)(av[j] - (float)h);
                }
                const f16x8 bh0 = *reinterpret_cast<const f16x8*>(whi + (size_t)((0 * 8 + s) * 64 + lane) * 8);
                const f16x8 bl0 = *reinterpret_cast<const f16x8*>(wlo + (size_t)((0 * 8 + s) * 64 + lane) * 8);
                const f16x8 bh1 = *reinterpret_cast<const f16x8*>(whi + (size_t)((1 * 8 + s) * 64 + lane) * 8);
                const f16x8 bl1 = *reinterpret_cast<const f16x8*>(wlo + (size_t)((1 * 8 + s) * 64 + lane) * 8);
                acc0 = __builtin_amdgcn_mfma_f32_16x16x32_f16(ah, bh0, acc0, 0, 0, 0);
                acc0 = __builtin_amdgcn_mfma_f32_16x16x32_f16(al, bh0, acc0, 0, 0, 0);
                acc0 = __builtin_amdgcn_mfma_f32_16x16x32_f16(ah, bl0, acc0, 0, 0, 0);
                acc1 = __builtin_amdgcn_mfma_f32_16x16x32_f16(ah, bh1, acc1, 0, 0, 0);
                acc1 = __builtin_amdgcn_mfma_f32_16x16x32_f16(al, bh1, acc1, 0, 0, 0);
                acc1 = __builtin_amdgcn_mfma_f32_16x16x32_f16(ah, bl1, acc1, 0, 0, 0);
            }
            // epilogue: the 4 D-regs are one pool quad; qq = pooled pos
            const int qq = (mt & 3) * 4 + g;
            float* orow = x2 + (size_t)(b0 + wv) * 320 + qq * 20;
            const float v0 = fmaxf(fmaxf(acc0[0], acc0[1]), fmaxf(acc0[2], acc0[3]));
            orow[c0] = selu_f(v0 + bias0);
            if (c0 < 4) {
                const float v1 = fmaxf(fmaxf(acc1[0], acc1[1]), fmaxf(acc1[2], acc1[3]));
                orow[16 + c0] = selu_f(v1 + bias1);
            }
        }
    }
}

// ---------------------------------------------------------------------------
// Kernel B: lin1 (320->50, permuted weights) + selu, lin2 (50->25) -> code
// ---------------------------------------------------------------------------
__global__ __launch_bounds__(256) void k_lin12(
    const float* __restrict__ x2,
    const float* __restrict__ lin1_wp, const float* __restrict__ lin1_b,
    const float* __restrict__ lin2_w,  const float* __restrict__ lin2_b,
    float* __restrict__ code)
{
    __shared__ float sIn[32][324];
    __shared__ float sH[32][51];
    const int t  = threadIdx.x;
    const int b0 = blockIdx.x * 32;
    {
        const float* g = x2 + (size_t)b0 * 320;
        for (int i = t; i < 32 * 320; i += 256) {
            const int r = i / 320;
            sIn[r][i - r * 320] = g[i];
        }
    }
    __syncthreads();

    for (int idx = t; idx < 1600; idx += 256) {        // 32 x 50
        const int bi = idx & 31;
        const int j  = idx >> 5;
        float s = lin1_b[j];
        const float4* w  = reinterpret_cast<const float4*>(lin1_wp + j * 320);
        const float4* xi = reinterpret_cast<const float4*>(&sIn[bi][0]);
        #pragma unroll 4
        for (int k4 = 0; k4 < 80; ++k4) {
            const float4 a = xi[k4];
            const float4 wq = w[k4];
            s = fmaf(a.x, wq.x, s); s = fmaf(a.y, wq.y, s);
            s = fmaf(a.z, wq.z, s); s = fmaf(a.w, wq.w, s);
        }
        sH[bi][j] = selu_f(s);
    }
    __syncthreads();
    for (int idx = t; idx < 800; idx += 256) {         // 32 x 25
        const int bi = idx & 31;
        const int j  = idx >> 5;
        float s = lin2_b[j];
        const float* w = lin2_w + j * 50;
        #pragma unroll
        for (int k = 0; k < 50; ++k) s = fmaf(sH[bi][k], w[k], s);
        code[(size_t)(b0 + bi) * 25 + j] = s;
    }
}

// ---------------------------------------------------------------------------
// Kernel C: per-sample 5x5: A = M*M^T, double Jacobi eigensolver,
//           P = sum of outer products of top-2 eigenvectors -> proj[B][25]
// ---------------------------------------------------------------------------
__global__ __launch_bounds__(64) void k_svdproj(
    const float* __restrict__ code, float* __restrict__ proj)
{
    const int b = blockIdx.x * 64 + threadIdx.x;
    if (b >= NB) return;
    const float* c = code + (size_t)b * 25;

    double M[5][5];
    #pragma unroll
    for (int i = 0; i < 5; ++i) {
        #pragma unroll
        for (int j = 0; j < 5; ++j) M[i][j] = (double)c[i * 5 + j];
    }
    double A[5][5], V[5][5];
    #pragma unroll
    for (int i = 0; i < 5; ++i) {
        #pragma unroll
        for (int j = 0; j < 5; ++j) {
            double s = 0.0;
            #pragma unroll
            for (int k = 0; k < 5; ++k) s += M[i][k] * M[j][k];
            A[i][j] = s;
            V[i][j] = (i == j) ? 1.0 : 0.0;
        }
    }
    for (int sweep = 0; sweep < 8; ++sweep) {
        #pragma unroll
        for (int p = 0; p < 4; ++p) {
            #pragma unroll
            for (int q = p + 1; q < 5; ++q) {
                const double apq = A[p][q];
                if (fabs(apq) > 1e-60) {
                    const double app = A[p][p], aqq = A[q][q];
                    const double tau = (aqq - app) / (2.0 * apq);
                    const double tt  = (tau >= 0.0 ? 1.0 : -1.0) /
                                       (fabs(tau) + sqrt(1.0 + tau * tau));
                    const double cc  = 1.0 / sqrt(1.0 + tt * tt);
                    const double ss  = tt * cc;
                    #pragma unroll
                    for (int i = 0; i < 5; ++i) {
                        if (i == p || i == q) continue;
                        const double aip = A[i][p], aiq = A[i][q];
                        A[i][p] = A[p][i] = cc * aip - ss * aiq;
                        A[i][q] = A[q][i] = ss * aip + cc * aiq;
                    }
                    A[p][p] = app - tt * apq;
                    A[q][q] = aqq + tt * apq;
                    A[p][q] = A[q][p] = 0.0;
                    #pragma unroll
                    for (int i = 0; i < 5; ++i) {
                        const double vip = V[i][p], viq = V[i][q];
                        V[i][p] = cc * vip - ss * viq;
                        V[i][q] = ss * vip + cc * viq;
                    }
                }
            }
        }
    }
    double d[5];
    #pragma unroll
    for (int i = 0; i < 5; ++i) d[i] = A[i][i];
    double sel[5];
    #pragma unroll
    for (int c1 = 0; c1 < 5; ++c1) {
        int cnt = 0;
        #pragma unroll
        for (int c2 = 0; c2 < 5; ++c2) {
            if (c2 == c1) continue;
            if (d[c2] > d[c1] || (d[c2] == d[c1] && c2 < c1)) ++cnt;
        }
        sel[c1] = (cnt < 2) ? 1.0 : 0.0;
    }
    #pragma unroll
    for (int i = 0; i < 5; ++i) {
        #pragma unroll
        for (int j = 0; j < 5; ++j) {
            double s = 0.0;
            #pragma unroll
            for (int k = 0; k < 5; ++k) s += sel[k] * V[i][k] * V[j][k];
            proj[(size_t)b * 25 + i * 5 + j] = (float)s;
        }
    }
}

// ---------------------------------------------------------------------------
// Kernel D: dec1 (25->160) + selu  ->  bf16 h in LDS  ->  dec2 (160->784)
//           via mfma_f32_16x16x32_bf16 + bias + sigmoid -> out[B][784]
// ---------------------------------------------------------------------------
#define HS 168   // padded h row stride in ushorts

__global__ __launch_bounds__(256) void k_decoder(
    const float* __restrict__ proj,
    const float* __restrict__ dec1_w, const float* __restrict__ dec1_b,
    const unsigned short* __restrict__ dec2_wb, const float* __restrict__ dec2_b,
    float* __restrict__ out)
{
    __shared__ unsigned short sH[32 * HS];
    const int t  = threadIdx.x;
    const int b0 = blockIdx.x * 32;
    const int bi = t & 31;     // sample row owned by this thread (phase 1)
    const int j0 = t >> 5;     // 0..7

    // ---- phase 1: h[bi][j] = selu(dec1), j = j0 + 8*i ----
    float p[25];
    {
        const float* pr = proj + (size_t)(b0 + bi) * 25;
        #pragma unroll
        for (int k = 0; k < 25; ++k) p[k] = pr[k];
    }
    #pragma unroll 4
    for (int i = 0; i < 20; ++i) {
        const int j = j0 + i * 8;
        const float* w = dec1_w + j * 25;
        float s = dec1_b[j];
        #pragma unroll
        for (int k = 0; k < 25; ++k) s = fmaf(p[k], w[k], s);
        sH[bi * HS + j] = f2bf(selu_f(s));
    }
    __syncthreads();

    // ---- phase 2: out[32][784] = sigmoid(h @ W^T + b) via MFMA ----
    const int wv   = t >> 6;      // 0..3
    const int lane = t & 63;
    const int arow = lane & 15;   // A row / B col within tile
    const int kgrp = lane >> 4;   // 0..3

    bf16x8 afr[2][5];             // hoisted A fragments: 2 row-tiles x 5 k-steps
    #pragma unroll
    for (int rt = 0; rt < 2; ++rt)
        #pragma unroll
        for (int ks = 0; ks < 5; ++ks)
            afr[rt][ks] = *reinterpret_cast<const bf16x8*>(
                &sH[(rt * 16 + arow) * HS + ks * 32 + kgrp * 8]);

    for (int ct = wv; ct < 49; ct += 4) {
        const int col = ct * 16 + arow;
        bf16x8 bfr[5];
        const unsigned short* wp = dec2_wb + (size_t)col * 160 + kgrp * 8;
        #pragma unroll
        for (int ks = 0; ks < 5; ++ks)
            bfr[ks] = *reinterpret_cast<const bf16x8*>(wp + ks * 32);

        f32x4 acc0 = {0.f, 0.f, 0.f, 0.f};
        f32x4 acc1 = {0.f, 0.f, 0.f, 0.f};
        #pragma unroll
        for (int ks = 0; ks < 5; ++ks) {
            acc0 = __builtin_amdgcn_mfma_f32_16x16x32_bf16(afr[0][ks], bfr[ks], acc0, 0, 0, 0);
            acc1 = __builtin_amdgcn_mfma_f32_16x16x32_bf16(afr[1][ks], bfr[ks], acc1, 0, 0, 0);
        }
        const float bb = dec2_b[col];
        #pragma unroll
        for (int r = 0; r < 4; ++r) {
            const int row = kgrp * 4 + r;          // D: row=(lane>>4)*4+reg
            const float v0 = acc0[r] + bb;
            const float v1 = acc1[r] + bb;
            out[(size_t)(b0 + row) * 784 + col]      = 1.0f / (1.0f + __expf(-v0));
            out[(size_t)(b0 + 16 + row) * 784 + col] = 1.0f / (1.0f + __expf(-v1));
        }
    }
}

// ---------------------------------------------------------------------------
extern "C" void kernel_launch(void* const* d_in, const int* in_sizes, int n_in,
                              void* d_out, int out_size, void* d_ws, size_t ws_size,
                              hipStream_t stream) {
    const float* images  = (const float*)d_in[0];
    const float* conv1_w = (const float*)d_in[1];
    const float* conv1_b = (const float*)d_in[2];
    const float* conv2_w = (const float*)d_in[3];
    const float* conv2_b = (const float*)d_in[4];
    const float* lin1_w  = (const float*)d_in[5];
    const float* lin1_b  = (const float*)d_in[6];
    const float* lin2_w  = (const float*)d_in[7];
    const float* lin2_b  = (const float*)d_in[8];
    const float* dec1_w  = (const float*)d_in[9];
    const float* dec1_b  = (const float*)d_in[10];
    const float* dec2_w  = (const float*)d_in[11];
    const float* dec2_b  = (const float*)d_in[12];

    float* out_img = (float*)d_out;                    // NB*784 fp32
    float* code    = (float*)d_out + (size_t)NB * 784; // NB*25  fp32

    // workspace layout (bytes, all 16-aligned):
    char* ws = (char*)d_ws;
    float*          x2      = (float*)ws;                                  // NB*320 f
    float*          proj    = (float*)(ws + (size_t)NB * 320 * 4);         // NB*25 f
    unsigned short* wbf     = (unsigned short*)(ws + (size_t)NB * 345 * 4);// 125440 us
    char*           pB      = ws + (size_t)NB * 345 * 4 + 250880;
    float*          lin1_wp = (float*)pB;                                  // 16000 f
    unsigned short* woff    = (unsigned short*)(pB + 64000);               // 256 us
    __fp16*         whi     = (__fp16*)(pB + 64512);                       // 8192 h
    __fp16*         wlo     = (__fp16*)(pB + 80896);                       // 8192 h

    k_prep     <<<618,      256, 0, stream>>>(dec2_w, wbf, lin1_w, lin1_wp,
                                              conv2_w, woff, whi, wlo);
    k_conv_fused<<<NB / 4,  256, 0, stream>>>(images, conv1_w, conv1_b,
                                              conv2_b, woff, whi, wlo, x2);
    k_lin12    <<<NB / 32, 256, 0, stream>>>(x2, lin1_wp, lin1_b,
                                             lin2_w, lin2_b, code);
    k_svdproj  <<<NB / 64, 64, 0, stream>>>(code, proj);
    k_decoder  <<<NB / 32, 256, 0, stream>>>(proj, dec1_w, dec1_b,
                                             wbf, dec2_b, out_img);
}

// Round 7
// 212.239 us; speedup vs baseline: 2.0867x; 2.0867x over previous
//
#include <hip/hip_runtime.h>
#include <hip/hip_bf16.h>
#include <math.h>

#define NB 16384

typedef __bf16 bf16x8 __attribute__((ext_vector_type(8)));
typedef __fp16 f16x8  __attribute__((ext_vector_type(8)));
typedef float  f32x4  __attribute__((ext_vector_type(4)));
typedef unsigned short ushort8 __attribute__((ext_vector_type(8)));

__device__ __forceinline__ float selu_f(float x) {
    const float kScale = 1.0507009873554805f;
    const float kAlphaScale = 1.7580993408473766f;   // scale*alpha
    return x > 0.0f ? kScale * x : kAlphaScale * (__expf(x) - 1.0f);
}

__device__ __forceinline__ unsigned short f2bf(float x) {   // RNE
    unsigned int u = __float_as_uint(x);
    unsigned int r = (u + 0x7FFFu + ((u >> 16) & 1u)) >> 16;
    return (unsigned short)r;
}

// ---------------------------------------------------------------------------
// Kernel P (prep): builds all weight-derived tables in ws.
//  1. dec2_w  -> bf16 wbf                               (125440)
//  2. lin1_w  -> lin1_wp permuted for new x2 layout     (16000)
//     x2 new layout: [b][q*20 + oc]  (old: oc*16 + q)
//  3. woff[k] -> x1 float offset of k-th conv2 reduction elem (256)
//  4. conv2_w -> whi/wlo fp16 split, B-fragment order   (2 x 8192)
//     layout: [(nt*8+s)*64 + lane]*8 + j  with oc = nt*16+(lane&15),
//             k = s*32 + (lane>>4)*8 + j
// ---------------------------------------------------------------------------
__global__ __launch_bounds__(256) void k_prep(
    const float* __restrict__ dec2_w,  unsigned short* __restrict__ wbf,
    const float* __restrict__ lin1_w,  float* __restrict__ lin1_wp,
    const float* __restrict__ conv2_w, unsigned short* __restrict__ woff,
    __fp16* __restrict__ whi, __fp16* __restrict__ wlo)
{
    int i = blockIdx.x * 256 + threadIdx.x;
    if (i < 125440) { wbf[i] = f2bf(dec2_w[i]); return; }
    i -= 125440;
    if (i < 16000) {                       // lin1 permute
        const int row = i / 320, cn = i - row * 320;
        const int q = cn / 20, oc = cn - q * 20;
        lin1_wp[row * 320 + cn] = lin1_w[row * 320 + oc * 16 + q];
        return;
    }
    i -= 16000;
    if (i < 256) {                         // A-gather offsets
        unsigned short off = 0;
        if (i < 250) {
            const int ic = i / 25, r = i - ic * 25, ky = r / 5, kx = r - ky * 5;
            off = (unsigned short)(ic * 144 + ky * 12 + kx);
        }
        woff[i] = off;
        return;
    }
    i -= 256;
    if (i < 16384) {                       // conv2 weight split tables
        const int v = i >> 13;             // 0 = hi, 1 = lo
        const int r = i & 8191;
        const int j = r & 7, lane = (r >> 3) & 63, s = (r >> 9) & 7, nt = r >> 12;
        const int k  = s * 32 + (lane >> 4) * 8 + j;
        const int oc = nt * 16 + (lane & 15);
        float w = 0.f;
        if (k < 250 && oc < 20) {
            const int ic = k / 25, rr = k - ic * 25;
            w = conv2_w[(oc * 10 + ic) * 25 + rr];
        }
        const __fp16 hi = (__fp16)w;
        if (v == 0) whi[r] = hi;
        else        wlo[r] = (__fp16)(w - (float)hi);
    }
}

// ---------------------------------------------------------------------------
// Kernel A: conv1(1->10,5x5)+pool+selu (fp32 VALU)  ->  sX1 in LDS  ->
//           conv2(10->20,5x5) as split-fp16 MFMA GEMM (M=256,N=2x16,K=8x32)
//           + pool + bias + selu  ->  x2[b][q*20+oc]
// Loop nest: s OUTER with #pragma unroll 1 + manual double-buffer of the 4
// B-fragments (r6 lesson: s-unrolled-inner let the scheduler hoist 32 b-frag
// loads = 128 VGPR -> spill -> 1.1GB scratch traffic, 2x regression).
// launch_bounds(256,4): do NOT raise (r4: (256,6) spilled, 10x regression).
// ---------------------------------------------------------------------------
#define X1S 1440

__global__ __launch_bounds__(256, 4) void k_conv_fused(
    const float* __restrict__ images,
    const float* __restrict__ conv1_w, const float* __restrict__ conv1_b,
    const float* __restrict__ conv2_b,
    const unsigned short* __restrict__ woff,
    const __fp16* __restrict__ whi, const __fp16* __restrict__ wlo,
    float* __restrict__ x2)
{
    __shared__ float sX1[4][X1S];

    const int t  = threadIdx.x;
    const int b0 = blockIdx.x * 4;

    // ---- phase 1: conv1 + pool + selu -> sX1[img][c*144 + pos] ----
    #pragma unroll
    for (int it = 0; it < 3; ++it) {
        const int item = it * 256 + t;
        if (item < 576) {
            const int img = item / 144;
            const int pos = item - img * 144;
            const int py  = pos / 12;
            const int px  = pos - py * 12;
            float p[36];
            const float* bp = images + (size_t)(b0 + img) * 784 + (2 * py) * 28 + 2 * px;
            #pragma unroll
            for (int r = 0; r < 6; ++r) {
                #pragma unroll
                for (int c2 = 0; c2 < 3; ++c2) {
                    const float2 v = *reinterpret_cast<const float2*>(bp + r * 28 + c2 * 2);
                    p[r * 6 + c2 * 2]     = v.x;
                    p[r * 6 + c2 * 2 + 1] = v.y;
                }
            }
            float* x1 = sX1[img];
            #pragma unroll
            for (int c = 0; c < 10; ++c) {
                const float* w = conv1_w + c * 25;   // uniform -> s_load
                float s0 = 0.f, s1 = 0.f, s2 = 0.f, s3 = 0.f;
                #pragma unroll
                for (int ky = 0; ky < 5; ++ky) {
                    #pragma unroll
                    for (int kx = 0; kx < 5; ++kx) {
                        const float wq = w[ky * 5 + kx];
                        s0 = fmaf(p[ky * 6 + kx],           wq, s0);
                        s1 = fmaf(p[ky * 6 + kx + 1],       wq, s1);
                        s2 = fmaf(p[(ky + 1) * 6 + kx],     wq, s2);
                        s3 = fmaf(p[(ky + 1) * 6 + kx + 1], wq, s3);
                    }
                }
                const float m = fmaxf(fmaxf(s0, s1), fmaxf(s2, s3)) + conv1_b[c];
                x1[c * 144 + pos] = selu_f(m);
            }
        }
    }
    __syncthreads();

    // ---- phase 2: conv2 via MFMA. wave w owns image w (4 m-tiles) ----
    {
        const int lane = t & 63;
        const int wv   = t >> 6;
        const float* x1 = sX1[wv];
        const int g  = lane >> 4;          // k-group
        const int c0 = lane & 15;          // B col within tile / D col

        // per-lane A-row base for each of the 4 m-tiles
        int rowbase[4];
        #pragma unroll
        for (int mi = 0; mi < 4; ++mi) {
            const int r64 = mi * 16 + c0;
            const int qi  = r64 >> 2;
            const int sub = r64 & 3;
            rowbase[mi] = (2 * (qi >> 2) + (sub >> 1)) * 12
                        + 2 * (qi & 3) + (sub & 1);
        }

        f32x4 acc[4][2];
        #pragma unroll
        for (int mi = 0; mi < 4; ++mi) {
            acc[mi][0] = (f32x4){0.f, 0.f, 0.f, 0.f};
            acc[mi][1] = (f32x4){0.f, 0.f, 0.f, 0.f};
        }

        // double-buffered per-s data (named regs; no runtime indexing)
        ushort8 off = *reinterpret_cast<const ushort8*>(woff + g * 8);
        f16x8 bh0 = *reinterpret_cast<const f16x8*>(whi + (size_t)(0 * 64 + lane) * 8);
        f16x8 bl0 = *reinterpret_cast<const f16x8*>(wlo + (size_t)(0 * 64 + lane) * 8);
        f16x8 bh1 = *reinterpret_cast<const f16x8*>(whi + (size_t)(8 * 64 + lane) * 8);
        f16x8 bl1 = *reinterpret_cast<const f16x8*>(wlo + (size_t)(8 * 64 + lane) * 8);

        #pragma unroll 1
        for (int s = 0; s < 8; ++s) {
            const int sn = (s + 1) & 7;    // wraps harmlessly at s=7
            const ushort8 offn = *reinterpret_cast<const ushort8*>(woff + sn * 32 + g * 8);
            const f16x8 nbh0 = *reinterpret_cast<const f16x8*>(whi + (size_t)((0 + sn) * 64 + lane) * 8);
            const f16x8 nbl0 = *reinterpret_cast<const f16x8*>(wlo + (size_t)((0 + sn) * 64 + lane) * 8);
            const f16x8 nbh1 = *reinterpret_cast<const f16x8*>(whi + (size_t)((8 + sn) * 64 + lane) * 8);
            const f16x8 nbl1 = *reinterpret_cast<const f16x8*>(wlo + (size_t)((8 + sn) * 64 + lane) * 8);

            #pragma unroll
            for (int mi = 0; mi < 4; ++mi) {
                float av[8];
                #pragma unroll
                for (int j = 0; j < 8; ++j)
                    av[j] = x1[rowbase[mi] + (int)off[j]];
                f16x8 ah, al;
                #pragma unroll
                for (int j = 0; j < 8; ++j) {
                    const __fp16 h = (__fp16)av[j];
                    ah[j] = h;
                    al[j] = (__fp16)(av[j] - (float)h);
                }
                acc[mi][0] = __builtin_amdgcn_mfma_f32_16x16x32_f16(ah, bh0, acc[mi][0], 0, 0, 0);
                acc[mi][0] = __builtin_amdgcn_mfma_f32_16x16x32_f16(al, bh0, acc[mi][0], 0, 0, 0);
                acc[mi][0] = __builtin_amdgcn_mfma_f32_16x16x32_f16(ah, bl0, acc[mi][0], 0, 0, 0);
                acc[mi][1] = __builtin_amdgcn_mfma_f32_16x16x32_f16(ah, bh1, acc[mi][1], 0, 0, 0);
                acc[mi][1] = __builtin_amdgcn_mfma_f32_16x16x32_f16(al, bh1, acc[mi][1], 0, 0, 0);
                acc[mi][1] = __builtin_amdgcn_mfma_f32_16x16x32_f16(ah, bl1, acc[mi][1], 0, 0, 0);
            }
            off = offn; bh0 = nbh0; bl0 = nbl0; bh1 = nbh1; bl1 = nbl1;
        }

        // epilogue: the 4 D-regs are one pool quad; qq = pooled pos
        const float bias0 = conv2_b[c0];
        const float bias1 = (c0 < 4) ? conv2_b[16 + c0] : 0.f;
        #pragma unroll
        for (int mi = 0; mi < 4; ++mi) {
            const int qq = mi * 4 + g;
            float* orow = x2 + (size_t)(b0 + wv) * 320 + qq * 20;
            const float v0 = fmaxf(fmaxf(acc[mi][0][0], acc[mi][0][1]),
                                   fmaxf(acc[mi][0][2], acc[mi][0][3]));
            orow[c0] = selu_f(v0 + bias0);
            if (c0 < 4) {
                const float v1 = fmaxf(fmaxf(acc[mi][1][0], acc[mi][1][1]),
                                       fmaxf(acc[mi][1][2], acc[mi][1][3]));
                orow[16 + c0] = selu_f(v1 + bias1);
            }
        }
    }
}

// ---------------------------------------------------------------------------
// Kernel B: lin1 (320->50, permuted weights) + selu, lin2 (50->25) -> code
// ---------------------------------------------------------------------------
__global__ __launch_bounds__(256) void k_lin12(
    const float* __restrict__ x2,
    const float* __restrict__ lin1_wp, const float* __restrict__ lin1_b,
    const float* __restrict__ lin2_w,  const float* __restrict__ lin2_b,
    float* __restrict__ code)
{
    __shared__ float sIn[32][324];
    __shared__ float sH[32][51];
    const int t  = threadIdx.x;
    const int b0 = blockIdx.x * 32;
    {
        const float* g = x2 + (size_t)b0 * 320;
        for (int i = t; i < 32 * 320; i += 256) {
            const int r = i / 320;
            sIn[r][i - r * 320] = g[i];
        }
    }
    __syncthreads();

    for (int idx = t; idx < 1600; idx += 256) {        // 32 x 50
        const int bi = idx & 31;
        const int j  = idx >> 5;
        float s = lin1_b[j];
        const float4* w  = reinterpret_cast<const float4*>(lin1_wp + j * 320);
        const float4* xi = reinterpret_cast<const float4*>(&sIn[bi][0]);
        #pragma unroll 4
        for (int k4 = 0; k4 < 80; ++k4) {
            const float4 a = xi[k4];
            const float4 wq = w[k4];
            s = fmaf(a.x, wq.x, s); s = fmaf(a.y, wq.y, s);
            s = fmaf(a.z, wq.z, s); s = fmaf(a.w, wq.w, s);
        }
        sH[bi][j] = selu_f(s);
    }
    __syncthreads();
    for (int idx = t; idx < 800; idx += 256) {         // 32 x 25
        const int bi = idx & 31;
        const int j  = idx >> 5;
        float s = lin2_b[j];
        const float* w = lin2_w + j * 50;
        #pragma unroll
        for (int k = 0; k < 50; ++k) s = fmaf(sH[bi][k], w[k], s);
        code[(size_t)(b0 + bi) * 25 + j] = s;
    }
}

// ---------------------------------------------------------------------------
// Kernel C: per-sample 5x5: A = M*M^T, double Jacobi eigensolver,
//           P = sum of outer products of top-2 eigenvectors -> proj[B][25]
// ---------------------------------------------------------------------------
__global__ __launch_bounds__(64) void k_svdproj(
    const float* __restrict__ code, float* __restrict__ proj)
{
    const int b = blockIdx.x * 64 + threadIdx.x;
    if (b >= NB) return;
    const float* c = code + (size_t)b * 25;

    double M[5][5];
    #pragma unroll
    for (int i = 0; i < 5; ++i) {
        #pragma unroll
        for (int j = 0; j < 5; ++j) M[i][j] = (double)c[i * 5 + j];
    }
    double A[5][5], V[5][5];
    #pragma unroll
    for (int i = 0; i < 5; ++i) {
        #pragma unroll
        for (int j = 0; j < 5; ++j) {
            double s = 0.0;
            #pragma unroll
            for (int k = 0; k < 5; ++k) s += M[i][k] * M[j][k];
            A[i][j] = s;
            V[i][j] = (i == j) ? 1.0 : 0.0;
        }
    }
    for (int sweep = 0; sweep < 8; ++sweep) {
        #pragma unroll
        for (int p = 0; p < 4; ++p) {
            #pragma unroll
            for (int q = p + 1; q < 5; ++q) {
                const double apq = A[p][q];
                if (fabs(apq) > 1e-60) {
                    const double app = A[p][p], aqq = A[q][q];
                    const double tau = (aqq - app) / (2.0 * apq);
                    const double tt  = (tau >= 0.0 ? 1.0 : -1.0) /
                                       (fabs(tau) + sqrt(1.0 + tau * tau));
                    const double cc  = 1.0 / sqrt(1.0 + tt * tt);
                    const double ss  = tt * cc;
                    #pragma unroll
                    for (int i = 0; i < 5; ++i) {
                        if (i == p || i == q) continue;
                        const double aip = A[i][p], aiq = A[i][q];
                        A[i][p] = A[p][i] = cc * aip - ss * aiq;
                        A[i][q] = A[q][i] = ss * aip + cc * aiq;
                    }
                    A[p][p] = app - tt * apq;
                    A[q][q] = aqq + tt * apq;
                    A[p][q] = A[q][p] = 0.0;
                    #pragma unroll
                    for (int i = 0; i < 5; ++i) {
                        const double vip = V[i][p], viq = V[i][q];
                        V[i][p] = cc * vip - ss * viq;
                        V[i][q] = ss * vip + cc * viq;
                    }
                }
            }
        }
    }
    double d[5];
    #pragma unroll
    for (int i = 0; i < 5; ++i) d[i] = A[i][i];
    double sel[5];
    #pragma unroll
    for (int c1 = 0; c1 < 5; ++c1) {
        int cnt = 0;
        #pragma unroll
        for (int c2 = 0; c2 < 5; ++c2) {
            if (c2 == c1) continue;
            if (d[c2] > d[c1] || (d[c2] == d[c1] && c2 < c1)) ++cnt;
        }
        sel[c1] = (cnt < 2) ? 1.0 : 0.0;
    }
    #pragma unroll
    for (int i = 0; i < 5; ++i) {
        #pragma unroll
        for (int j = 0; j < 5; ++j) {
            double s = 0.0;
            #pragma unroll
            for (int k = 0; k < 5; ++k) s += sel[k] * V[i][k] * V[j][k];
            proj[(size_t)b * 25 + i * 5 + j] = (float)s;
        }
    }
}

// ---------------------------------------------------------------------------
// Kernel D: dec1 (25->160) + selu  ->  bf16 h in LDS  ->  dec2 (160->784)
//           via mfma_f32_16x16x32_bf16 + bias + sigmoid -> out[B][784]
// ---------------------------------------------------------------------------
#define HS 168   // padded h row stride in ushorts

__global__ __launch_bounds__(256) void k_decoder(
    const float* __restrict__ proj,
    const float* __restrict__ dec1_w, const float* __restrict__ dec1_b,
    const unsigned short* __restrict__ dec2_wb, const float* __restrict__ dec2_b,
    float* __restrict__ out)
{
    __shared__ unsigned short sH[32 * HS];
    const int t  = threadIdx.x;
    const int b0 = blockIdx.x * 32;
    const int bi = t & 31;     // sample row owned by this thread (phase 1)
    const int j0 = t >> 5;     // 0..7

    // ---- phase 1: h[bi][j] = selu(dec1), j = j0 + 8*i ----
    float p[25];
    {
        const float* pr = proj + (size_t)(b0 + bi) * 25;
        #pragma unroll
        for (int k = 0; k < 25; ++k) p[k] = pr[k];
    }
    #pragma unroll 4
    for (int i = 0; i < 20; ++i) {
        const int j = j0 + i * 8;
        const float* w = dec1_w + j * 25;
        float s = dec1_b[j];
        #pragma unroll
        for (int k = 0; k < 25; ++k) s = fmaf(p[k], w[k], s);
        sH[bi * HS + j] = f2bf(selu_f(s));
    }
    __syncthreads();

    // ---- phase 2: out[32][784] = sigmoid(h @ W^T + b) via MFMA ----
    const int wv   = t >> 6;      // 0..3
    const int lane = t & 63;
    const int arow = lane & 15;   // A row / B col within tile
    const int kgrp = lane >> 4;   // 0..3

    bf16x8 afr[2][5];             // hoisted A fragments: 2 row-tiles x 5 k-steps
    #pragma unroll
    for (int rt = 0; rt < 2; ++rt)
        #pragma unroll
        for (int ks = 0; ks < 5; ++ks)
            afr[rt][ks] = *reinterpret_cast<const bf16x8*>(
                &sH[(rt * 16 + arow) * HS + ks * 32 + kgrp * 8]);

    for (int ct = wv; ct < 49; ct += 4) {
        const int col = ct * 16 + arow;
        bf16x8 bfr[5];
        const unsigned short* wp = dec2_wb + (size_t)col * 160 + kgrp * 8;
        #pragma unroll
        for (int ks = 0; ks < 5; ++ks)
            bfr[ks] = *reinterpret_cast<const bf16x8*>(wp + ks * 32);

        f32x4 acc0 = {0.f, 0.f, 0.f, 0.f};
        f32x4 acc1 = {0.f, 0.f, 0.f, 0.f};
        #pragma unroll
        for (int ks = 0; ks < 5; ++ks) {
            acc0 = __builtin_amdgcn_mfma_f32_16x16x32_bf16(afr[0][ks], bfr[ks], acc0, 0, 0, 0);
            acc1 = __builtin_amdgcn_mfma_f32_16x16x32_bf16(afr[1][ks], bfr[ks], acc1, 0, 0, 0);
        }
        const float bb = dec2_b[col];
        #pragma unroll
        for (int r = 0; r < 4; ++r) {
            const int row = kgrp * 4 + r;          // D: row=(lane>>4)*4+reg
            const float v0 = acc0[r] + bb;
            const float v1 = acc1[r] + bb;
            out[(size_t)(b0 + row) * 784 + col]      = 1.0f / (1.0f + __expf(-v0));
            out[(size_t)(b0 + 16 + row) * 784 + col] = 1.0f / (1.0f + __expf(-v1));
        }
    }
}

// ---------------------------------------------------------------------------
extern "C" void kernel_launch(void* const* d_in, const int* in_sizes, int n_in,
                              void* d_out, int out_size, void* d_ws, size_t ws_size,
                              hipStream_t stream) {
    const float* images  = (const float*)d_in[0];
    const float* conv1_w = (const float*)d_in[1];
    const float* conv1_b = (const float*)d_in[2];
    const float* conv2_w = (const float*)d_in[3];
    const float* conv2_b = (const float*)d_in[4];
    const float* lin1_w  = (const float*)d_in[5];
    const float* lin1_b  = (const float*)d_in[6];
    const float* lin2_w  = (const float*)d_in[7];
    const float* lin2_b  = (const float*)d_in[8];
    const float* dec1_w  = (const float*)d_in[9];
    const float* dec1_b  = (const float*)d_in[10];
    const float* dec2_w  = (const float*)d_in[11];
    const float* dec2_b  = (const float*)d_in[12];

    float* out_img = (float*)d_out;                    // NB*784 fp32
    float* code    = (float*)d_out + (size_t)NB * 784; // NB*25  fp32

    // workspace layout (bytes, all 16-aligned):
    char* ws = (char*)d_ws;
    float*          x2      = (float*)ws;                                  // NB*320 f
    float*          proj    = (float*)(ws + (size_t)NB * 320 * 4);         // NB*25 f
    unsigned short* wbf     = (unsigned short*)(ws + (size_t)NB * 345 * 4);// 125440 us
    char*           pB      = ws + (size_t)NB * 345 * 4 + 250880;
    float*          lin1_wp = (float*)pB;                                  // 16000 f
    unsigned short* woff    = (unsigned short*)(pB + 64000);               // 256 us
    __fp16*         whi     = (__fp16*)(pB + 64512);                       // 8192 h
    __fp16*         wlo     = (__fp16*)(pB + 80896);                       // 8192 h

    k_prep     <<<618,      256, 0, stream>>>(dec2_w, wbf, lin1_w, lin1_wp,
                                              conv2_w, woff, whi, wlo);
    k_conv_fused<<<NB / 4,  256, 0, stream>>>(images, conv1_w, conv1_b,
                                              conv2_b, woff, whi, wlo, x2);
    k_lin12    <<<NB / 32, 256, 0, stream>>>(x2, lin1_wp, lin1_b,
                                             lin2_w, lin2_b, code);
    k_svdproj  <<<NB / 64, 64, 0, stream>>>(code, proj);
    k_decoder  <<<NB / 32, 256, 0, stream>>>(proj, dec1_w, dec1_b,
                                             wbf, dec2_b, out_img);
}

// Round 8
// 198.664 us; speedup vs baseline: 2.2293x; 1.0683x over previous
//
#include <hip/hip_runtime.h>
#include <hip/hip_bf16.h>
#include <math.h>

#define NB 16384

typedef __bf16 bf16x8 __attribute__((ext_vector_type(8)));
typedef __fp16 f16x8  __attribute__((ext_vector_type(8)));
typedef float  f32x4  __attribute__((ext_vector_type(4)));
typedef unsigned short ushort8 __attribute__((ext_vector_type(8)));
typedef unsigned int   uint4v  __attribute__((ext_vector_type(4)));

__device__ __forceinline__ float selu_f(float x) {
    const float kScale = 1.0507009873554805f;
    const float kAlphaScale = 1.7580993408473766f;   // scale*alpha
    return x > 0.0f ? kScale * x : kAlphaScale * (__expf(x) - 1.0f);
}

__device__ __forceinline__ unsigned short f2bf(float x) {   // RNE
    unsigned int u = __float_as_uint(x);
    unsigned int r = (u + 0x7FFFu + ((u >> 16) & 1u)) >> 16;
    return (unsigned short)r;
}

// split v into fp16 hi + fp16 lo, packed into one u32 (lo16=hi, hi16=lo)
__device__ __forceinline__ unsigned int packsplit(float v) {
    const __fp16 h = (__fp16)v;
    const __fp16 l = (__fp16)(v - (float)h);
    const unsigned int hb = (unsigned int)__builtin_bit_cast(unsigned short, h);
    const unsigned int lb = (unsigned int)__builtin_bit_cast(unsigned short, l);
    return hb | (lb << 16);
}

// extract packed pairs: AH u32 = {w1.lo16, w0.lo16}, AL u32 = {w1.hi16, w0.hi16}
#define PERM_AH 0x05040100u
#define PERM_AL 0x07060302u

union F16x8Cast { uint4v u; f16x8 f; };

#define CH1 145          // x1 channel stride (17c mod 32 distinct -> bank spread)
#define X1SZ (CH1 * 10)  // 1450 u32 per image

// ---------------------------------------------------------------------------
// Kernel P (prep): builds all weight-derived tables in ws.
//  1. dec2_w  -> bf16 wbf                               (125440)
//  2. lin1_w  -> lin1_wp permuted for x2 [b][q*20+oc]   (16000)
//  3. woff[k] -> x1P u32-offset of conv2 k-elem, stride CH1 (256)
//  4. conv2_w -> whi/wlo fp16 split, B-fragment order   (2 x 8192)
//  5. koff1[k]-> image u32-offset of conv1 k-elem       (32)
//  6. conv1_w -> whi1/wlo1 fp16 split, B-fragment order (2 x 512)
// ---------------------------------------------------------------------------
__global__ __launch_bounds__(256) void k_prep(
    const float* __restrict__ dec2_w,  unsigned short* __restrict__ wbf,
    const float* __restrict__ lin1_w,  float* __restrict__ lin1_wp,
    const float* __restrict__ conv2_w, unsigned short* __restrict__ woff,
    __fp16* __restrict__ whi, __fp16* __restrict__ wlo,
    const float* __restrict__ conv1_w, unsigned short* __restrict__ koff1,
    __fp16* __restrict__ whi1, __fp16* __restrict__ wlo1)
{
    int i = blockIdx.x * 256 + threadIdx.x;
    if (i < 125440) { wbf[i] = f2bf(dec2_w[i]); return; }
    i -= 125440;
    if (i < 16000) {                       // lin1 permute
        const int row = i / 320, cn = i - row * 320;
        const int q = cn / 20, oc = cn - q * 20;
        lin1_wp[row * 320 + cn] = lin1_w[row * 320 + oc * 16 + q];
        return;
    }
    i -= 16000;
    if (i < 256) {                         // conv2 A-gather offsets (stride CH1)
        unsigned short off = 0;
        if (i < 250) {
            const int ic = i / 25, r = i - ic * 25, ky = r / 5, kx = r - ky * 5;
            off = (unsigned short)(ic * CH1 + ky * 12 + kx);
        }
        woff[i] = off;
        return;
    }
    i -= 256;
    if (i < 16384) {                       // conv2 weight split tables
        const int v = i >> 13;             // 0 = hi, 1 = lo
        const int r = i & 8191;
        const int j = r & 7, lane = (r >> 3) & 63, s = (r >> 9) & 7, nt = r >> 12;
        const int k  = s * 32 + (lane >> 4) * 8 + j;
        const int oc = nt * 16 + (lane & 15);
        float w = 0.f;
        if (k < 250 && oc < 20) {
            const int ic = k / 25, rr = k - ic * 25;
            w = conv2_w[(oc * 10 + ic) * 25 + rr];
        }
        const __fp16 hi = (__fp16)w;
        if (v == 0) whi[r] = hi;
        else        wlo[r] = (__fp16)(w - (float)hi);
        return;
    }
    i -= 16384;
    if (i < 32) {                          // conv1 A-gather offsets (image, stride 28)
        unsigned short off = 0;
        if (i < 25) off = (unsigned short)((i / 5) * 28 + (i % 5));
        koff1[i] = off;
        return;
    }
    i -= 32;
    if (i < 1024) {                        // conv1 weight split tables
        const int v = i >> 9;
        const int r = i & 511;
        const int j = r & 7, lane = r >> 3;
        const int c = lane & 15, g = lane >> 4;
        const int k = g * 8 + j;
        float w = 0.f;
        if (k < 25 && c < 10) w = conv1_w[c * 25 + k];
        const __fp16 hi = (__fp16)w;
        if (v == 0) whi1[r] = hi;
        else        wlo1[r] = (__fp16)(w - (float)hi);
    }
}

// ---------------------------------------------------------------------------
// Kernel A: conv1 AND conv2 both as split-fp16 MFMA GEMMs. 4 images/block,
// wave w owns image w.
//  phase 0: images -> split-packed u32 in LDS (sImgP)
//  phase 1: conv1 GEMM  M=16x(12a+4b) quad-major, K=32(25), N=16(10);
//           pool+bias+selu in D-regs -> split-packed x1 (sX1P, stride CH1)
//  phase 2: conv2 GEMM as r7 (proven), gather+v_perm extraction (no cvt)
// Split a=ah+al, b=bh+bl; ah*bh+al*bh+ah*bl ~ fp32-class (2^-22 rel).
// launch_bounds(256,4): do NOT raise (r4 spill lesson). Keep loop live-sets
// small (r6 lesson: wide unrolled load-hoists spill at the 128-VGPR cap).
// ---------------------------------------------------------------------------
__global__ __launch_bounds__(256, 4) void k_conv_fused(
    const float* __restrict__ images,
    const float* __restrict__ conv1_b, const float* __restrict__ conv2_b,
    const unsigned short* __restrict__ woff,
    const __fp16* __restrict__ whi,  const __fp16* __restrict__ wlo,
    const unsigned short* __restrict__ koff1,
    const __fp16* __restrict__ whi1, const __fp16* __restrict__ wlo1,
    float* __restrict__ x2)
{
    __shared__ unsigned int sImgP[4 * 784];    // 12.5 KB
    __shared__ unsigned int sX1P[4 * X1SZ];    // 23.2 KB

    const int t  = threadIdx.x;
    const int b0 = blockIdx.x * 4;

    // ---- phase 0: images -> split-packed LDS ----
    for (int i = t; i < 4 * 784; i += 256)
        sImgP[i] = packsplit(images[(size_t)b0 * 784 + i]);
    __syncthreads();

    const int lane = t & 63;
    const int wv   = t >> 6;
    const int g    = lane >> 4;          // k-group
    const int c0   = lane & 15;          // A-row (phase1/2) / D-col

    // ---- phase 1: conv1 via MFMA -> sX1P[wv][c*CH1 + q] ----
    {
        const unsigned int* imgP = sImgP + wv * 784;
        unsigned int* x1P = sX1P + wv * X1SZ;

        // per-lane A base: row r=c0 -> quad r>>2, sub r&3
        const int sub = c0 & 3, qq = c0 >> 2;
        const int base_lane = (sub >> 1) * 28 + 2 * qq + (sub & 1);
        const ushort8 kof = *reinterpret_cast<const ushort8*>(koff1 + g * 8);
        int addr8[8];
        #pragma unroll
        for (int j = 0; j < 8; ++j) addr8[j] = base_lane + (int)kof[j];

        const f16x8 bh1 = *reinterpret_cast<const f16x8*>(whi1 + lane * 8);
        const f16x8 bl1 = *reinterpret_cast<const f16x8*>(wlo1 + lane * 8);
        const float bias = (c0 < 10) ? conv1_b[c0] : 0.f;

        #pragma unroll 1
        for (int a = 0; a < 12; ++a) {
            const int abase = a * 56;
            #pragma unroll
            for (int b = 0; b < 3; ++b) {
                unsigned int w[8];
                #pragma unroll
                for (int j = 0; j < 8; ++j)
                    w[j] = imgP[addr8[j] + abase + b * 8];
                F16x8Cast AH, AL;
                AH.u = (uint4v){ __builtin_amdgcn_perm(w[1], w[0], PERM_AH),
                                 __builtin_amdgcn_perm(w[3], w[2], PERM_AH),
                                 __builtin_amdgcn_perm(w[5], w[4], PERM_AH),
                                 __builtin_amdgcn_perm(w[7], w[6], PERM_AH) };
                AL.u = (uint4v){ __builtin_amdgcn_perm(w[1], w[0], PERM_AL),
                                 __builtin_amdgcn_perm(w[3], w[2], PERM_AL),
                                 __builtin_amdgcn_perm(w[5], w[4], PERM_AL),
                                 __builtin_amdgcn_perm(w[7], w[6], PERM_AL) };
                f32x4 acc = {0.f, 0.f, 0.f, 0.f};
                acc = __builtin_amdgcn_mfma_f32_16x16x32_f16(AH.f, bh1, acc, 0, 0, 0);
                acc = __builtin_amdgcn_mfma_f32_16x16x32_f16(AL.f, bh1, acc, 0, 0, 0);
                acc = __builtin_amdgcn_mfma_f32_16x16x32_f16(AH.f, bl1, acc, 0, 0, 0);
                // D: col=c0 (channel), rows g*4+0..3 = subs of quad q=12a+4b+g
                const float m = fmaxf(fmaxf(acc[0], acc[1]), fmaxf(acc[2], acc[3]));
                const unsigned int pv = packsplit(selu_f(m + bias));
                if (c0 < 10)
                    x1P[c0 * CH1 + 12 * a + 4 * b + g] = pv;
            }
        }
    }
    __syncthreads();

    // ---- phase 2: conv2 via MFMA (r7 structure, perm extraction) ----
    {
        const unsigned int* x1P = sX1P + wv * X1SZ;

        int rowbase[4];
        #pragma unroll
        for (int mi = 0; mi < 4; ++mi) {
            const int r64 = mi * 16 + c0;
            const int qi  = r64 >> 2;
            const int sb  = r64 & 3;
            rowbase[mi] = (2 * (qi >> 2) + (sb >> 1)) * 12
                        + 2 * (qi & 3) + (sb & 1);
        }

        f32x4 acc[4][2];
        #pragma unroll
        for (int mi = 0; mi < 4; ++mi) {
            acc[mi][0] = (f32x4){0.f, 0.f, 0.f, 0.f};
            acc[mi][1] = (f32x4){0.f, 0.f, 0.f, 0.f};
        }

        // double-buffered per-s data (named regs; no runtime indexing)
        ushort8 off = *reinterpret_cast<const ushort8*>(woff + g * 8);
        f16x8 bh0 = *reinterpret_cast<const f16x8*>(whi + (size_t)(0 * 64 + lane) * 8);
        f16x8 bl0 = *reinterpret_cast<const f16x8*>(wlo + (size_t)(0 * 64 + lane) * 8);
        f16x8 bh1 = *reinterpret_cast<const f16x8*>(whi + (size_t)(8 * 64 + lane) * 8);
        f16x8 bl1 = *reinterpret_cast<const f16x8*>(wlo + (size_t)(8 * 64 + lane) * 8);

        #pragma unroll 1
        for (int s = 0; s < 8; ++s) {
            const int sn = (s + 1) & 7;    // wraps harmlessly at s=7
            const ushort8 offn = *reinterpret_cast<const ushort8*>(woff + sn * 32 + g * 8);
            const f16x8 nbh0 = *reinterpret_cast<const f16x8*>(whi + (size_t)((0 + sn) * 64 + lane) * 8);
            const f16x8 nbl0 = *reinterpret_cast<const f16x8*>(wlo + (size_t)((0 + sn) * 64 + lane) * 8);
            const f16x8 nbh1 = *reinterpret_cast<const f16x8*>(whi + (size_t)((8 + sn) * 64 + lane) * 8);
            const f16x8 nbl1 = *reinterpret_cast<const f16x8*>(wlo + (size_t)((8 + sn) * 64 + lane) * 8);

            #pragma unroll
            for (int mi = 0; mi < 4; ++mi) {
                unsigned int w[8];
                #pragma unroll
                for (int j = 0; j < 8; ++j)
                    w[j] = x1P[rowbase[mi] + (int)off[j]];
                F16x8Cast AH, AL;
                AH.u = (uint4v){ __builtin_amdgcn_perm(w[1], w[0], PERM_AH),
                                 __builtin_amdgcn_perm(w[3], w[2], PERM_AH),
                                 __builtin_amdgcn_perm(w[5], w[4], PERM_AH),
                                 __builtin_amdgcn_perm(w[7], w[6], PERM_AH) };
                AL.u = (uint4v){ __builtin_amdgcn_perm(w[1], w[0], PERM_AL),
                                 __builtin_amdgcn_perm(w[3], w[2], PERM_AL),
                                 __builtin_amdgcn_perm(w[5], w[4], PERM_AL),
                                 __builtin_amdgcn_perm(w[7], w[6], PERM_AL) };
                acc[mi][0] = __builtin_amdgcn_mfma_f32_16x16x32_f16(AH.f, bh0, acc[mi][0], 0, 0, 0);
                acc[mi][0] = __builtin_amdgcn_mfma_f32_16x16x32_f16(AL.f, bh0, acc[mi][0], 0, 0, 0);
                acc[mi][0] = __builtin_amdgcn_mfma_f32_16x16x32_f16(AH.f, bl0, acc[mi][0], 0, 0, 0);
                acc[mi][1] = __builtin_amdgcn_mfma_f32_16x16x32_f16(AH.f, bh1, acc[mi][1], 0, 0, 0);
                acc[mi][1] = __builtin_amdgcn_mfma_f32_16x16x32_f16(AL.f, bh1, acc[mi][1], 0, 0, 0);
                acc[mi][1] = __builtin_amdgcn_mfma_f32_16x16x32_f16(AH.f, bl1, acc[mi][1], 0, 0, 0);
            }
            off = offn; bh0 = nbh0; bl0 = nbl0; bh1 = nbh1; bl1 = nbl1;
        }

        // epilogue: the 4 D-regs are one pool quad; qq = pooled pos
        const float bias0 = conv2_b[c0];
        const float bias1 = (c0 < 4) ? conv2_b[16 + c0] : 0.f;
        #pragma unroll
        for (int mi = 0; mi < 4; ++mi) {
            const int qq = mi * 4 + g;
            float* orow = x2 + (size_t)(b0 + wv) * 320 + qq * 20;
            const float v0 = fmaxf(fmaxf(acc[mi][0][0], acc[mi][0][1]),
                                   fmaxf(acc[mi][0][2], acc[mi][0][3]));
            orow[c0] = selu_f(v0 + bias0);
            if (c0 < 4) {
                const float v1 = fmaxf(fmaxf(acc[mi][1][0], acc[mi][1][1]),
                                       fmaxf(acc[mi][1][2], acc[mi][1][3]));
                orow[16 + c0] = selu_f(v1 + bias1);
            }
        }
    }
}

// ---------------------------------------------------------------------------
// Kernel B: lin1 (320->50, permuted weights) + selu, lin2 (50->25) -> code
// ---------------------------------------------------------------------------
__global__ __launch_bounds__(256) void k_lin12(
    const float* __restrict__ x2,
    const float* __restrict__ lin1_wp, const float* __restrict__ lin1_b,
    const float* __restrict__ lin2_w,  const float* __restrict__ lin2_b,
    float* __restrict__ code)
{
    __shared__ float sIn[32][324];
    __shared__ float sH[32][51];
    const int t  = threadIdx.x;
    const int b0 = blockIdx.x * 32;
    {
        const float* g = x2 + (size_t)b0 * 320;
        for (int i = t; i < 32 * 320; i += 256) {
            const int r = i / 320;
            sIn[r][i - r * 320] = g[i];
        }
    }
    __syncthreads();

    for (int idx = t; idx < 1600; idx += 256) {        // 32 x 50
        const int bi = idx & 31;
        const int j  = idx >> 5;
        float s = lin1_b[j];
        const float4* w  = reinterpret_cast<const float4*>(lin1_wp + j * 320);
        const float4* xi = reinterpret_cast<const float4*>(&sIn[bi][0]);
        #pragma unroll 4
        for (int k4 = 0; k4 < 80; ++k4) {
            const float4 a = xi[k4];
            const float4 wq = w[k4];
            s = fmaf(a.x, wq.x, s); s = fmaf(a.y, wq.y, s);
            s = fmaf(a.z, wq.z, s); s = fmaf(a.w, wq.w, s);
        }
        sH[bi][j] = selu_f(s);
    }
    __syncthreads();
    for (int idx = t; idx < 800; idx += 256) {         // 32 x 25
        const int bi = idx & 31;
        const int j  = idx >> 5;
        float s = lin2_b[j];
        const float* w = lin2_w + j * 50;
        #pragma unroll
        for (int k = 0; k < 50; ++k) s = fmaf(sH[bi][k], w[k], s);
        code[(size_t)(b0 + bi) * 25 + j] = s;
    }
}

// ---------------------------------------------------------------------------
// Kernel C: per-sample 5x5: A = M*M^T, double Jacobi eigensolver,
//           P = sum of outer products of top-2 eigenvectors -> proj[B][25]
// ---------------------------------------------------------------------------
__global__ __launch_bounds__(64) void k_svdproj(
    const float* __restrict__ code, float* __restrict__ proj)
{
    const int b = blockIdx.x * 64 + threadIdx.x;
    if (b >= NB) return;
    const float* c = code + (size_t)b * 25;

    double M[5][5];
    #pragma unroll
    for (int i = 0; i < 5; ++i) {
        #pragma unroll
        for (int j = 0; j < 5; ++j) M[i][j] = (double)c[i * 5 + j];
    }
    double A[5][5], V[5][5];
    #pragma unroll
    for (int i = 0; i < 5; ++i) {
        #pragma unroll
        for (int j = 0; j < 5; ++j) {
            double s = 0.0;
            #pragma unroll
            for (int k = 0; k < 5; ++k) s += M[i][k] * M[j][k];
            A[i][j] = s;
            V[i][j] = (i == j) ? 1.0 : 0.0;
        }
    }
    for (int sweep = 0; sweep < 8; ++sweep) {
        #pragma unroll
        for (int p = 0; p < 4; ++p) {
            #pragma unroll
            for (int q = p + 1; q < 5; ++q) {
                const double apq = A[p][q];
                if (fabs(apq) > 1e-60) {
                    const double app = A[p][p], aqq = A[q][q];
                    const double tau = (aqq - app) / (2.0 * apq);
                    const double tt  = (tau >= 0.0 ? 1.0 : -1.0) /
                                       (fabs(tau) + sqrt(1.0 + tau * tau));
                    const double cc  = 1.0 / sqrt(1.0 + tt * tt);
                    const double ss  = tt * cc;
                    #pragma unroll
                    for (int i = 0; i < 5; ++i) {
                        if (i == p || i == q) continue;
                        const double aip = A[i][p], aiq = A[i][q];
                        A[i][p] = A[p][i] = cc * aip - ss * aiq;
                        A[i][q] = A[q][i] = ss * aip + cc * aiq;
                    }
                    A[p][p] = app - tt * apq;
                    A[q][q] = aqq + tt * apq;
                    A[p][q] = A[q][p] = 0.0;
                    #pragma unroll
                    for (int i = 0; i < 5; ++i) {
                        const double vip = V[i][p], viq = V[i][q];
                        V[i][p] = cc * vip - ss * viq;
                        V[i][q] = ss * vip + cc * viq;
                    }
                }
            }
        }
    }
    double d[5];
    #pragma unroll
    for (int i = 0; i < 5; ++i) d[i] = A[i][i];
    double sel[5];
    #pragma unroll
    for (int c1 = 0; c1 < 5; ++c1) {
        int cnt = 0;
        #pragma unroll
        for (int c2 = 0; c2 < 5; ++c2) {
            if (c2 == c1) continue;
            if (d[c2] > d[c1] || (d[c2] == d[c1] && c2 < c1)) ++cnt;
        }
        sel[c1] = (cnt < 2) ? 1.0 : 0.0;
    }
    #pragma unroll
    for (int i = 0; i < 5; ++i) {
        #pragma unroll
        for (int j = 0; j < 5; ++j) {
            double s = 0.0;
            #pragma unroll
            for (int k = 0; k < 5; ++k) s += sel[k] * V[i][k] * V[j][k];
            proj[(size_t)b * 25 + i * 5 + j] = (float)s;
        }
    }
}

// ---------------------------------------------------------------------------
// Kernel D: dec1 (25->160) + selu  ->  bf16 h in LDS  ->  dec2 (160->784)
//           via mfma_f32_16x16x32_bf16 + bias + sigmoid -> out[B][784]
// ---------------------------------------------------------------------------
#define HS 168   // padded h row stride in ushorts

__global__ __launch_bounds__(256) void k_decoder(
    const float* __restrict__ proj,
    const float* __restrict__ dec1_w, const float* __restrict__ dec1_b,
    const unsigned short* __restrict__ dec2_wb, const float* __restrict__ dec2_b,
    float* __restrict__ out)
{
    __shared__ unsigned short sH[32 * HS];
    const int t  = threadIdx.x;
    const int b0 = blockIdx.x * 32;
    const int bi = t & 31;     // sample row owned by this thread (phase 1)
    const int j0 = t >> 5;     // 0..7

    // ---- phase 1: h[bi][j] = selu(dec1), j = j0 + 8*i ----
    float p[25];
    {
        const float* pr = proj + (size_t)(b0 + bi) * 25;
        #pragma unroll
        for (int k = 0; k < 25; ++k) p[k] = pr[k];
    }
    #pragma unroll 4
    for (int i = 0; i < 20; ++i) {
        const int j = j0 + i * 8;
        const float* w = dec1_w + j * 25;
        float s = dec1_b[j];
        #pragma unroll
        for (int k = 0; k < 25; ++k) s = fmaf(p[k], w[k], s);
        sH[bi * HS + j] = f2bf(selu_f(s));
    }
    __syncthreads();

    // ---- phase 2: out[32][784] = sigmoid(h @ W^T + b) via MFMA ----
    const int wv   = t >> 6;      // 0..3
    const int lane = t & 63;
    const int arow = lane & 15;   // A row / B col within tile
    const int kgrp = lane >> 4;   // 0..3

    bf16x8 afr[2][5];             // hoisted A fragments: 2 row-tiles x 5 k-steps
    #pragma unroll
    for (int rt = 0; rt < 2; ++rt)
        #pragma unroll
        for (int ks = 0; ks < 5; ++ks)
            afr[rt][ks] = *reinterpret_cast<const bf16x8*>(
                &sH[(rt * 16 + arow) * HS + ks * 32 + kgrp * 8]);

    for (int ct = wv; ct < 49; ct += 4) {
        const int col = ct * 16 + arow;
        bf16x8 bfr[5];
        const unsigned short* wp = dec2_wb + (size_t)col * 160 + kgrp * 8;
        #pragma unroll
        for (int ks = 0; ks < 5; ++ks)
            bfr[ks] = *reinterpret_cast<const bf16x8*>(wp + ks * 32);

        f32x4 acc0 = {0.f, 0.f, 0.f, 0.f};
        f32x4 acc1 = {0.f, 0.f, 0.f, 0.f};
        #pragma unroll
        for (int ks = 0; ks < 5; ++ks) {
            acc0 = __builtin_amdgcn_mfma_f32_16x16x32_bf16(afr[0][ks], bfr[ks], acc0, 0, 0, 0);
            acc1 = __builtin_amdgcn_mfma_f32_16x16x32_bf16(afr[1][ks], bfr[ks], acc1, 0, 0, 0);
        }
        const float bb = dec2_b[col];
        #pragma unroll
        for (int r = 0; r < 4; ++r) {
            const int row = kgrp * 4 + r;          // D: row=(lane>>4)*4+reg
            const float v0 = acc0[r] + bb;
            const float v1 = acc1[r] + bb;
            out[(size_t)(b0 + row) * 784 + col]      = 1.0f / (1.0f + __expf(-v0));
            out[(size_t)(b0 + 16 + row) * 784 + col] = 1.0f / (1.0f + __expf(-v1));
        }
    }
}

// ---------------------------------------------------------------------------
extern "C" void kernel_launch(void* const* d_in, const int* in_sizes, int n_in,
                              void* d_out, int out_size, void* d_ws, size_t ws_size,
                              hipStream_t stream) {
    const float* images  = (const float*)d_in[0];
    const float* conv1_w = (const float*)d_in[1];
    const float* conv1_b = (const float*)d_in[2];
    const float* conv2_w = (const float*)d_in[3];
    const float* conv2_b = (const float*)d_in[4];
    const float* lin1_w  = (const float*)d_in[5];
    const float* lin1_b  = (const float*)d_in[6];
    const float* lin2_w  = (const float*)d_in[7];
    const float* lin2_b  = (const float*)d_in[8];
    const float* dec1_w  = (const float*)d_in[9];
    const float* dec1_b  = (const float*)d_in[10];
    const float* dec2_w  = (const float*)d_in[11];
    const float* dec2_b  = (const float*)d_in[12];

    float* out_img = (float*)d_out;                    // NB*784 fp32
    float* code    = (float*)d_out + (size_t)NB * 784; // NB*25  fp32

    // workspace layout (bytes, all 16-aligned):
    char* ws = (char*)d_ws;
    float*          x2      = (float*)ws;                                  // NB*320 f
    float*          proj    = (float*)(ws + (size_t)NB * 320 * 4);         // NB*25 f
    unsigned short* wbf     = (unsigned short*)(ws + (size_t)NB * 345 * 4);// 125440 us
    char*           pB      = ws + (size_t)NB * 345 * 4 + 250880;
    float*          lin1_wp = (float*)pB;                                  // 16000 f
    unsigned short* woff    = (unsigned short*)(pB + 64000);               // 256 us
    __fp16*         whi     = (__fp16*)(pB + 64512);                       // 8192 h
    __fp16*         wlo     = (__fp16*)(pB + 80896);                       // 8192 h
    unsigned short* koff1   = (unsigned short*)(pB + 97280);               // 32 us
    __fp16*         whi1    = (__fp16*)(pB + 97344);                       // 512 h
    __fp16*         wlo1    = (__fp16*)(pB + 98368);                       // 512 h

    k_prep     <<<622,      256, 0, stream>>>(dec2_w, wbf, lin1_w, lin1_wp,
                                              conv2_w, woff, whi, wlo,
                                              conv1_w, koff1, whi1, wlo1);
    k_conv_fused<<<NB / 4,  256, 0, stream>>>(images, conv1_b, conv2_b,
                                              woff, whi, wlo,
                                              koff1, whi1, wlo1, x2);
    k_lin12    <<<NB / 32, 256, 0, stream>>>(x2, lin1_wp, lin1_b,
                                             lin2_w, lin2_b, code);
    k_svdproj  <<<NB / 64, 64, 0, stream>>>(code, proj);
    k_decoder  <<<NB / 32, 256, 0, stream>>>(proj, dec1_w, dec1_b,
                                             wbf, dec2_b, out_img);
}